// Round 12
// baseline (305.498 us; speedup 1.0000x reference)
//
#include <hip/hip_runtime.h>

#define N_NODES 100000
#define N_EDGES 1600000
#define IN_C    64
#define HID_C   128
#define OUT_C   64
#define N_CLS   20

#define BUCKETS 196          // ceil(N_NODES / 512), 512 nodes per bucket
#define XSL     8            // one slice per XCD (blockIdx & 7)
#define WCAP    2560         // per (bucket,xcd) window; mean 1020, huge margin
#define EPB     4096         // edges per binA block
#define CAPB    44           // per-block per-bucket LDS cap; mean 20.9, +5sig

#define CVT_BLOCKS 3125      // N_NODES*64/8/256

typedef __attribute__((ext_vector_type(8))) short short8;   // 8 bf16 = 4 VGPR
typedef __attribute__((ext_vector_type(4))) float floatx4;  // MFMA acc

__device__ __forceinline__ unsigned short f2bf(float f) {  // RNE
    union { float f; unsigned u; } v; v.f = f;
    unsigned r = v.u + 0x7FFFu + ((v.u >> 16) & 1u);
    return (unsigned short)(r >> 16);
}
__device__ __forceinline__ unsigned pk2(float lo, float hi) {
    return (unsigned)f2bf(lo) | ((unsigned)f2bf(hi) << 16);
}
__device__ __forceinline__ float bflo(unsigned w) { return __uint_as_float(w << 16); }
__device__ __forceinline__ float bfhi(unsigned w) { return __uint_as_float(w & 0xFFFF0000u); }

#define ACC8(v) do { \
    a0 += bflo((v).x); a1 += bfhi((v).x); a2 += bflo((v).y); a3 += bfhi((v).y); \
    a4 += bflo((v).z); a5 += bfhi((v).z); a6 += bflo((v).w); a7 += bfhi((v).w); } while (0)

// ---- prologue: cvt_x + prep_wt + zero bcnt in one launch ------------------
__global__ __launch_bounds__(256) void prologue_kernel(
        const float* __restrict__ x,
        const float* __restrict__ ws1, const float* __restrict__ wn1,
        const float* __restrict__ ws2, const float* __restrict__ wn2,
        unsigned short* __restrict__ xb,
        unsigned short* __restrict__ wt1s, unsigned short* __restrict__ wt1n,
        unsigned short* __restrict__ wt2s, unsigned short* __restrict__ wt2n,
        int* __restrict__ bcnt)
{
    const int bid = blockIdx.x, tid = threadIdx.x;
    if (bid < CVT_BLOCKS) {
        int i = bid * 256 + tid;              // < 800000 exactly
        float4 a = ((const float4*)x)[(size_t)i * 2];
        float4 b = ((const float4*)x)[(size_t)i * 2 + 1];
        uint4 r;
        r.x = pk2(a.x, a.y); r.y = pk2(a.z, a.w);
        r.z = pk2(b.x, b.y); r.w = pk2(b.z, b.w);
        ((uint4*)xb)[i] = r;
    } else if (bid == CVT_BLOCKS) {
        for (int i = tid; i < BUCKETS * XSL; i += 256) bcnt[i] = 0;
    } else {
        int i = (bid - CVT_BLOCKS - 1) * 256 + tid;
        if (i < 8192) {                       // layer 1: [128][64]
            int o = i >> 6, c = i & 63;
            wt1s[i] = f2bf(ws1[c * 128 + o]);
            wt1n[i] = f2bf(wn1[c * 128 + o]);
        } else if (i < 16384) {               // layer 2: [64][128]
            int j = i - 8192;
            int o = j >> 7, c = j & 127;
            wt2s[j] = f2bf(ws2[c * 64 + o]);
            wt2n[j] = f2bf(wn2[c * 64 + o]);
        }
    }
}

// ---- CSR build: binned counting sort --------------------------------------
__global__ __launch_bounds__(256) void binA_kernel(
        const int* __restrict__ ei, int* __restrict__ bcnt,
        unsigned* __restrict__ bins)
{
    __shared__ unsigned lbins[BUCKETS * CAPB];
    __shared__ unsigned comp[EPB];
    __shared__ unsigned dsti[EPB];
    __shared__ int lcnt[BUCKETS], lofs[BUCKETS], gb[BUCKETS];
    __shared__ int sd[256];

    const int tid = threadIdx.x;
    const int xcd = blockIdx.x & (XSL - 1);
    const int e0  = blockIdx.x * EPB;

    for (int w = tid; w < BUCKETS; w += 256) lcnt[w] = 0;
    __syncthreads();

    for (int it = 0; it < EPB / 256; ++it) {
        int e = e0 + it * 256 + tid;
        if (e >= N_EDGES) break;
        int src = ei[e];
        int dst = ei[N_EDGES + e];
        int b = dst >> 9;
        unsigned pk = ((unsigned)(dst & 511) << 17) | (unsigned)src;
        int pos = atomicAdd(&lcnt[b], 1);
        if (pos < CAPB) {
            lbins[b * CAPB + pos] = pk;
        } else {  // rare fallback: direct global append (always correct)
            int gp = atomicAdd(&bcnt[b * XSL + xcd], 1);
            if (gp < WCAP)
                bins[(unsigned)(b * XSL + xcd) * WCAP + gp] = pk;
        }
    }
    __syncthreads();

    int c = (tid < BUCKETS) ? min(lcnt[tid], CAPB) : 0;
    sd[tid] = c;
    __syncthreads();
    for (int off = 1; off < 256; off <<= 1) {
        int x = 0;
        if (tid >= off) x = sd[tid - off];
        __syncthreads();
        if (tid >= off) sd[tid] += x;
        __syncthreads();
    }
    if (tid < BUCKETS) lofs[tid] = sd[tid] - c;
    __syncthreads();
    const int T = sd[255];

    if (tid < BUCKETS) {
        int cw = min(lcnt[tid], CAPB);
        gb[tid] = (cw > 0) ? atomicAdd(&bcnt[tid * XSL + xcd], cw) : 0;
    }
    __syncthreads();

    if (tid < BUCKETS) {
        int cw = min(lcnt[tid], CAPB);
        int lo = lofs[tid];
        unsigned wb = (unsigned)(tid * XSL + xcd) * WCAP + (unsigned)gb[tid];
        for (int i = 0; i < cw; ++i) {
            comp[lo + i] = lbins[tid * CAPB + i];
            dsti[lo + i] = wb + i;
        }
    }
    __syncthreads();

    for (int i = tid; i < T; i += 256)
        bins[dsti[i]] = comp[i];
}

// buildB with self-computed bucket base
__global__ __launch_bounds__(256) void buildB_kernel(
        const int* __restrict__ bcnt, const unsigned* __restrict__ bins,
        int* __restrict__ row_ptr, int* __restrict__ sorted_src,
        float* __restrict__ dinv)
{
    __shared__ unsigned ent[16384];
    __shared__ int scnt[XSL], soff[XSL];
    __shared__ int cnt[512], lofs[512], cur[512];
    __shared__ int sd[256];
    __shared__ int gbase_s;

    const int b   = blockIdx.x;
    const int tid = threadIdx.x;
    const int node0 = b * 512;

    int part = 0;
    for (int w = tid; w < b * XSL; w += 256) part += min(bcnt[w], WCAP);
    sd[tid] = part;
    __syncthreads();
    for (int off = 128; off > 0; off >>= 1) {
        if (tid < off) sd[tid] += sd[tid + off];
        __syncthreads();
    }
    if (tid == 0) {
        gbase_s = sd[0];
        if (b == 0) row_ptr[N_NODES] = N_EDGES;
    }
    __syncthreads();

    if (tid < XSL) scnt[tid] = min(bcnt[b * XSL + tid], WCAP);
    { int i = tid; cnt[i] = 0; cnt[i + 256] = 0; }
    __syncthreads();
    if (tid == 0) {
        int acc = 0;
        for (int sl = 0; sl < XSL; ++sl) {
            soff[sl] = acc;
            acc += scnt[sl];
            if (acc > 16384) { scnt[sl] -= (acc - 16384); acc = 16384; } // unreachable
        }
    }
    __syncthreads();

    for (int sl = 0; sl < XSL; ++sl) {
        int len = scnt[sl];
        const unsigned* seg = bins + (unsigned)(b * XSL + sl) * WCAP;
        int base = soff[sl];
        for (int i = tid; i < len; i += 256) {
            unsigned e = seg[i];
            ent[base + i] = e;
            atomicAdd((unsigned*)&cnt[e >> 17], 1u);
        }
    }
    __syncthreads();
    const int T = soff[XSL - 1] + scnt[XSL - 1];

    int a0 = cnt[2 * tid], a1 = cnt[2 * tid + 1];
    int s2 = a0 + a1;
    sd[tid] = s2;
    __syncthreads();
    for (int off = 1; off < 256; off <<= 1) {
        int x = 0;
        if (tid >= off) x = sd[tid - off];
        __syncthreads();
        if (tid >= off) sd[tid] += x;
        __syncthreads();
    }
    int excl = sd[tid] - s2;
    lofs[2 * tid]     = excl;
    lofs[2 * tid + 1] = excl + a0;
    cur[2 * tid]      = excl;
    cur[2 * tid + 1]  = excl + a0;
    __syncthreads();

    const int gbase = gbase_s;
    for (int j = tid; j < 512; j += 256) {
        int node = node0 + j;
        if (node < N_NODES) {
            row_ptr[node] = gbase + lofs[j];
            dinv[node] = 1.0f / (float)max(cnt[j], 1);
        }
    }
    for (int i = tid; i < T; i += 256) {
        unsigned e = ent[i];
        int dl = e >> 17;
        int p = atomicAdd((unsigned*)&cur[dl], 1u);
        sorted_src[gbase + p] = (int)(e & 0x1FFFFu);
    }
}

// ---- gather1: mean(xb[src]) -> agg1b (standalone, round-7 proven shape) ---
// 8 threads/node, 16B/thread (128B contiguous per node), 4x unroll.
// Grid 3125 x 256 == 8*N exactly: no guards.
__global__ __launch_bounds__(256) void gather1_kernel(
        const int* __restrict__ row_ptr, const int* __restrict__ srcs,
        const unsigned short* __restrict__ featb,  // [N][64] bf16
        const float* __restrict__ dinv, unsigned short* __restrict__ aggb)
{
    int gid = blockIdx.x * 256 + threadIdx.x;
    int n = gid >> 3;
    int q = gid & 7;
    const uint4* f4 = (const uint4*)featb;
    float a0=0,a1=0,a2=0,a3=0,a4=0,a5=0,a6=0,a7=0;
    int beg = row_ptr[n];
    int end = row_ptr[n + 1];
    int e = beg;
    for (; e + 4 <= end; e += 4) {
        int s0 = srcs[e], s1 = srcs[e+1], s2 = srcs[e+2], s3 = srcs[e+3];
        uint4 v0 = f4[(size_t)s0 * 8 + q];
        uint4 v1 = f4[(size_t)s1 * 8 + q];
        uint4 v2 = f4[(size_t)s2 * 8 + q];
        uint4 v3 = f4[(size_t)s3 * 8 + q];
        ACC8(v0); ACC8(v1); ACC8(v2); ACC8(v3);
    }
    for (; e < end; ++e) {
        uint4 v = f4[(size_t)srcs[e] * 8 + q];
        ACC8(v);
    }
    float di = dinv[n];
    uint4 r;
    r.x = pk2(a0 * di, a1 * di);
    r.y = pk2(a2 * di, a3 * di);
    r.z = pk2(a4 * di, a5 * di);
    r.w = pk2(a6 * di, a7 * di);
    ((uint4*)aggb)[(size_t)n * 8 + q] = r;
}

// ---- mlp1: dense1 -> h1(LDS) -> {t2 = Wn2.h1; s2 = Ws2.h1 + b2} -----------
// Pure MFMA kernel (no gather phase). 256 threads / 32 nodes / 3125 blocks
// (grid exact). Wave-pairs (0,2)/(1,3) own nodes 0-15/16-31; m-tiles split.
__global__ __launch_bounds__(256, 8) void mlp1_kernel(
        const unsigned short* __restrict__ xb,    // [N][64]
        const unsigned short* __restrict__ aggb,  // [N][64]
        const unsigned short* __restrict__ wt1s,  // [128][64]
        const unsigned short* __restrict__ wt1n,  // [128][64]
        const float* __restrict__ b1,             // [128]
        const unsigned short* __restrict__ wt2n,  // [64][128]
        const unsigned short* __restrict__ wt2s,  // [64][128]
        const float* __restrict__ b2,             // [64]
        unsigned short* __restrict__ t2b,         // [N][64]
        unsigned short* __restrict__ s2b)         // [N][64]
{
    __shared__ unsigned short sbuf[32 * 136];   // h1 (pitch 136 shorts)

    const int tid = threadIdx.x;
    const int node0 = blockIdx.x * 32;

    const int lane  = tid & 63;
    const int wv    = tid >> 6;              // 0..3
    const int quad  = lane >> 4;
    const int col   = lane & 15;
    const int nrow  = (wv & 1) * 16 + col;   // local node 0..31
    const int mhalf = wv >> 1;               // 0..1
    const int nl = node0 + nrow;

    // ---- phase B: dense1 ----
    {
        const short8 bs0 = *(const short8*)(xb   + (size_t)nl * 64 +      quad * 8);
        const short8 bs1 = *(const short8*)(xb   + (size_t)nl * 64 + 32 + quad * 8);
        const short8 bn0 = *(const short8*)(aggb + (size_t)nl * 64 +      quad * 8);
        const short8 bn1 = *(const short8*)(aggb + (size_t)nl * 64 + 32 + quad * 8);

#pragma unroll
        for (int mt = 0; mt < 4; ++mt) {
            int mb = mhalf * 4 + mt;         // 0..7 m-tile of 8
            int m = mb * 16 + col;
            const short8 as0 = *(const short8*)(wt1s + (size_t)m * 64 +      quad * 8);
            const short8 as1 = *(const short8*)(wt1s + (size_t)m * 64 + 32 + quad * 8);
            const short8 an0 = *(const short8*)(wt1n + (size_t)m * 64 +      quad * 8);
            const short8 an1 = *(const short8*)(wt1n + (size_t)m * 64 + 32 + quad * 8);
            floatx4 acc = {0.f, 0.f, 0.f, 0.f};
            acc = __builtin_amdgcn_mfma_f32_16x16x32_bf16(as0, bs0, acc, 0, 0, 0);
            acc = __builtin_amdgcn_mfma_f32_16x16x32_bf16(as1, bs1, acc, 0, 0, 0);
            acc = __builtin_amdgcn_mfma_f32_16x16x32_bf16(an0, bn0, acc, 0, 0, 0);
            acc = __builtin_amdgcn_mfma_f32_16x16x32_bf16(an1, bn1, acc, 0, 0, 0);
            int och = mb * 16 + quad * 4;
            float4 bv = *(const float4*)(b1 + och);
            ushort4 r;
            r.x = f2bf(fmaxf(acc[0] + bv.x, 0.f));
            r.y = f2bf(fmaxf(acc[1] + bv.y, 0.f));
            r.z = f2bf(fmaxf(acc[2] + bv.z, 0.f));
            r.w = f2bf(fmaxf(acc[3] + bv.w, 0.f));
            *(ushort4*)(sbuf + nrow * 136 + och) = r;
        }
    }
    __syncthreads();

    // ---- phase C: t2 = Wn2.h1 ; s2 = Ws2.h1 + b2 (m-tiles split by mhalf) --
    {
        short8 bfr[4];
#pragma unroll
        for (int kc = 0; kc < 4; ++kc)
            bfr[kc] = *(const short8*)(sbuf + nrow * 136 + kc * 32 + quad * 8);

#pragma unroll
        for (int mt = 0; mt < 2; ++mt) {
            int mb = mhalf * 2 + mt;         // 0..3 m-tile of 4
            int m = mb * 16 + col;
            floatx4 at = {0.f, 0.f, 0.f, 0.f};
            floatx4 as = {0.f, 0.f, 0.f, 0.f};
#pragma unroll
            for (int kc = 0; kc < 4; ++kc) {
                const short8 an = *(const short8*)(wt2n + (size_t)m * 128 + kc * 32 + quad * 8);
                const short8 aw = *(const short8*)(wt2s + (size_t)m * 128 + kc * 32 + quad * 8);
                at = __builtin_amdgcn_mfma_f32_16x16x32_bf16(an, bfr[kc], at, 0, 0, 0);
                as = __builtin_amdgcn_mfma_f32_16x16x32_bf16(aw, bfr[kc], as, 0, 0, 0);
            }
            int och = mb * 16 + quad * 4;
            ushort4 rt;
            rt.x = f2bf(at[0]); rt.y = f2bf(at[1]);
            rt.z = f2bf(at[2]); rt.w = f2bf(at[3]);
            *(ushort4*)(t2b + (size_t)nl * 64 + och) = rt;
            float4 bv = *(const float4*)(b2 + och);
            ushort4 rs;
            rs.x = f2bf(as[0] + bv.x); rs.y = f2bf(as[1] + bv.y);
            rs.z = f2bf(as[2] + bv.z); rs.w = f2bf(as[3] + bv.w);
            *(ushort4*)(s2b + (size_t)nl * 64 + och) = rs;
        }
    }
}

// ---- fused2: gather(t2) + relu(s2+agg) -> classifier ----------------------
// 256 threads / 32 nodes / 3125 blocks; one node per 8-thread group.
// Epilogue is ~4% of block time so phase-coherence penalty is negligible.
__global__ __launch_bounds__(256, 8) void fused2_kernel(
        const int* __restrict__ row_ptr, const int* __restrict__ srcs,
        const unsigned short* __restrict__ t2b,   // [N][64]
        const unsigned short* __restrict__ s2b,   // [N][64]
        const float* __restrict__ dinv,
        const float* __restrict__ wc,             // [64][20]
        const float* __restrict__ bc,             // [20]
        float* __restrict__ out)                  // [N][20]
{
    __shared__ float hs[32][68];

    const int tid = threadIdx.x;
    const int node0 = blockIdx.x * 32;

    // ---- phase A: gather mean(t2[src]) + s2 + relu -> hs (fp32) ----
    {
        const int q  = tid & 7;
        const int np = tid >> 3;   // 0..31
        const int n = node0 + np;
        const uint4* f4 = (const uint4*)t2b;
        float a0=0,a1=0,a2=0,a3=0,a4=0,a5=0,a6=0,a7=0;
        int beg = row_ptr[n];
        int end = row_ptr[n + 1];
        int e = beg;
        for (; e + 4 <= end; e += 4) {
            int s0 = srcs[e], s1 = srcs[e+1], s2 = srcs[e+2], s3 = srcs[e+3];
            uint4 v0 = f4[(size_t)s0 * 8 + q];
            uint4 v1 = f4[(size_t)s1 * 8 + q];
            uint4 v2 = f4[(size_t)s2 * 8 + q];
            uint4 v3 = f4[(size_t)s3 * 8 + q];
            ACC8(v0); ACC8(v1); ACC8(v2); ACC8(v3);
        }
        for (; e < end; ++e) {
            uint4 v = f4[(size_t)srcs[e] * 8 + q];
            ACC8(v);
        }
        float di = dinv[n];
        uint4 sv = *(const uint4*)(s2b + (size_t)n * 64 + q * 8);
        float* d = hs[np] + q * 8;
        d[0] = fmaxf(a0 * di + bflo(sv.x), 0.f);
        d[1] = fmaxf(a1 * di + bfhi(sv.x), 0.f);
        d[2] = fmaxf(a2 * di + bflo(sv.y), 0.f);
        d[3] = fmaxf(a3 * di + bfhi(sv.y), 0.f);
        d[4] = fmaxf(a4 * di + bflo(sv.z), 0.f);
        d[5] = fmaxf(a5 * di + bfhi(sv.z), 0.f);
        d[6] = fmaxf(a6 * di + bflo(sv.w), 0.f);
        d[7] = fmaxf(a7 * di + bfhi(sv.w), 0.f);
    }
    __syncthreads();

    // ---- phase B: classifier (wc/bc direct from global, L1-hot) ----
    for (int o = tid; o < 32 * N_CLS; o += 256) {
        int n = o / N_CLS, cls = o % N_CLS;
        float s = bc[cls];
#pragma unroll
        for (int k = 0; k < 64; ++k) s += hs[n][k] * wc[k * N_CLS + cls];
        out[(size_t)(node0 + n) * N_CLS + cls] = s;
    }
}

// ---------------------------------------------------------------------------

extern "C" void kernel_launch(void* const* d_in, const int* in_sizes, int n_in,
                              void* d_out, int out_size, void* d_ws, size_t ws_size,
                              hipStream_t stream)
{
    const float* x        = (const float*)d_in[0];
    const int*   ei       = (const int*)  d_in[1];
    const float* w_self1  = (const float*)d_in[2];
    const float* w_neigh1 = (const float*)d_in[3];
    const float* b1       = (const float*)d_in[4];
    const float* w_self2  = (const float*)d_in[5];
    const float* w_neigh2 = (const float*)d_in[6];
    const float* b2       = (const float*)d_in[7];
    const float* wc       = (const float*)d_in[8];
    const float* bc       = (const float*)d_in[9];
    float* out = (float*)d_out;

    const size_t N = N_NODES;
    int*      bcnt    = (int*)d_ws;                       // BUCKETS*XSL
    int*      row_ptr = bcnt + BUCKETS * XSL + 8;         // N+8
    unsigned* bins    = (unsigned*)(row_ptr + N + 8);     // BUCKETS*XSL*WCAP
    int*      s_src   = (int*)(bins + BUCKETS * XSL * WCAP);  // E
    float*    dinv    = (float*)(s_src + N_EDGES);        // N
    unsigned short* xb    = (unsigned short*)(dinv + N);  // [N][64]
    unsigned short* agg1b = xb + 64 * N;                  // [N][64]
    unsigned short* t2b   = agg1b + 64 * N;               // [N][64]
    unsigned short* s2b   = t2b + 64 * N;                 // [N][64]
    unsigned short* wt1s  = s2b + 64 * N;                 // 128x64
    unsigned short* wt1n  = wt1s + 8192;
    unsigned short* wt2s  = wt1n + 8192;                  // 64x128
    unsigned short* wt2n  = wt2s + 8192;

    const int PB  = CVT_BLOCKS + 1 + 64;           // prologue blocks
    const int EB2 = (N_EDGES + EPB - 1) / EPB;     // 391
    const int GB  = (N_NODES * 8) / 256;           // 3125 (exact)
    const int MB32 = (N_NODES + 31) / 32;          // 3125 (exact)

    prologue_kernel<<<PB, 256, 0, stream>>>(x, w_self1, w_neigh1, w_self2,
                                            w_neigh2, xb, wt1s, wt1n, wt2s,
                                            wt2n, bcnt);
    binA_kernel<<<EB2, 256, 0, stream>>>(ei, bcnt, bins);
    buildB_kernel<<<BUCKETS, 256, 0, stream>>>(bcnt, bins, row_ptr, s_src, dinv);
    gather1_kernel<<<GB, 256, 0, stream>>>(row_ptr, s_src, xb, dinv, agg1b);
    mlp1_kernel<<<MB32, 256, 0, stream>>>(xb, agg1b, wt1s, wt1n, b1,
                                          wt2n, wt2s, b2, t2b, s2b);
    fused2_kernel<<<MB32, 256, 0, stream>>>(row_ptr, s_src, t2b, s2b, dinv,
                                            wc, bc, out);
}

// Round 13
// 263.688 us; speedup vs baseline: 1.1586x; 1.1586x over previous
//
#include <hip/hip_runtime.h>

#define N_NODES 100000
#define N_EDGES 1600000
#define IN_C    64
#define HID_C   128
#define OUT_C   64
#define N_CLS   20

#define BUCKETS 196          // ceil(N_NODES / 512), 512 nodes per bucket
#define XSL     8            // one slice per XCD (blockIdx & 7)
#define WCAP    2560         // per (bucket,xcd) window; mean 1020, huge margin
#define EPB     4096         // edges per binA block
#define CAPB    44           // per-block per-bucket LDS cap; mean 20.9, +5sig

#define CVT_BLOCKS 3125      // N_NODES*64/8/256
#define NTILES    3125       // 32-node tiles (exact)
#define MLP_GRID  512        // persistent mlp blocks (2 per CU)

typedef __attribute__((ext_vector_type(8))) short short8;   // 8 bf16 = 4 VGPR
typedef __attribute__((ext_vector_type(4))) float floatx4;  // MFMA acc

__device__ __forceinline__ unsigned short f2bf(float f) {  // RNE
    union { float f; unsigned u; } v; v.f = f;
    unsigned r = v.u + 0x7FFFu + ((v.u >> 16) & 1u);
    return (unsigned short)(r >> 16);
}
__device__ __forceinline__ unsigned pk2(float lo, float hi) {
    return (unsigned)f2bf(lo) | ((unsigned)f2bf(hi) << 16);
}
__device__ __forceinline__ float bflo(unsigned w) { return __uint_as_float(w << 16); }
__device__ __forceinline__ float bfhi(unsigned w) { return __uint_as_float(w & 0xFFFF0000u); }

#define ACC8(v) do { \
    a0 += bflo((v).x); a1 += bfhi((v).x); a2 += bflo((v).y); a3 += bfhi((v).y); \
    a4 += bflo((v).z); a5 += bfhi((v).z); a6 += bflo((v).w); a7 += bfhi((v).w); } while (0)

// ---- prologue: cvt_x + prep_wt + zero bcnt in one launch ------------------
__global__ __launch_bounds__(256) void prologue_kernel(
        const float* __restrict__ x,
        const float* __restrict__ ws1, const float* __restrict__ wn1,
        const float* __restrict__ ws2, const float* __restrict__ wn2,
        unsigned short* __restrict__ xb,
        unsigned short* __restrict__ wt1s, unsigned short* __restrict__ wt1n,
        unsigned short* __restrict__ wt2s, unsigned short* __restrict__ wt2n,
        int* __restrict__ bcnt)
{
    const int bid = blockIdx.x, tid = threadIdx.x;
    if (bid < CVT_BLOCKS) {
        int i = bid * 256 + tid;              // < 800000 exactly
        float4 a = ((const float4*)x)[(size_t)i * 2];
        float4 b = ((const float4*)x)[(size_t)i * 2 + 1];
        uint4 r;
        r.x = pk2(a.x, a.y); r.y = pk2(a.z, a.w);
        r.z = pk2(b.x, b.y); r.w = pk2(b.z, b.w);
        ((uint4*)xb)[i] = r;
    } else if (bid == CVT_BLOCKS) {
        for (int i = tid; i < BUCKETS * XSL; i += 256) bcnt[i] = 0;
    } else {
        int i = (bid - CVT_BLOCKS - 1) * 256 + tid;
        if (i < 8192) {                       // layer 1: [128][64]
            int o = i >> 6, c = i & 63;
            wt1s[i] = f2bf(ws1[c * 128 + o]);
            wt1n[i] = f2bf(wn1[c * 128 + o]);
        } else if (i < 16384) {               // layer 2: [64][128]
            int j = i - 8192;
            int o = j >> 7, c = j & 127;
            wt2s[j] = f2bf(ws2[c * 64 + o]);
            wt2n[j] = f2bf(wn2[c * 64 + o]);
        }
    }
}

// ---- CSR build: binned counting sort --------------------------------------
__global__ __launch_bounds__(256) void binA_kernel(
        const int* __restrict__ ei, int* __restrict__ bcnt,
        unsigned* __restrict__ bins)
{
    __shared__ unsigned lbins[BUCKETS * CAPB];
    __shared__ unsigned comp[EPB];
    __shared__ unsigned dsti[EPB];
    __shared__ int lcnt[BUCKETS], lofs[BUCKETS], gb[BUCKETS];
    __shared__ int sd[256];

    const int tid = threadIdx.x;
    const int xcd = blockIdx.x & (XSL - 1);
    const int e0  = blockIdx.x * EPB;

    for (int w = tid; w < BUCKETS; w += 256) lcnt[w] = 0;
    __syncthreads();

    for (int it = 0; it < EPB / 256; ++it) {
        int e = e0 + it * 256 + tid;
        if (e >= N_EDGES) break;
        int src = ei[e];
        int dst = ei[N_EDGES + e];
        int b = dst >> 9;
        unsigned pk = ((unsigned)(dst & 511) << 17) | (unsigned)src;
        int pos = atomicAdd(&lcnt[b], 1);
        if (pos < CAPB) {
            lbins[b * CAPB + pos] = pk;
        } else {  // rare fallback: direct global append (always correct)
            int gp = atomicAdd(&bcnt[b * XSL + xcd], 1);
            if (gp < WCAP)
                bins[(unsigned)(b * XSL + xcd) * WCAP + gp] = pk;
        }
    }
    __syncthreads();

    int c = (tid < BUCKETS) ? min(lcnt[tid], CAPB) : 0;
    sd[tid] = c;
    __syncthreads();
    for (int off = 1; off < 256; off <<= 1) {
        int x = 0;
        if (tid >= off) x = sd[tid - off];
        __syncthreads();
        if (tid >= off) sd[tid] += x;
        __syncthreads();
    }
    if (tid < BUCKETS) lofs[tid] = sd[tid] - c;
    __syncthreads();
    const int T = sd[255];

    if (tid < BUCKETS) {
        int cw = min(lcnt[tid], CAPB);
        gb[tid] = (cw > 0) ? atomicAdd(&bcnt[tid * XSL + xcd], cw) : 0;
    }
    __syncthreads();

    if (tid < BUCKETS) {
        int cw = min(lcnt[tid], CAPB);
        int lo = lofs[tid];
        unsigned wb = (unsigned)(tid * XSL + xcd) * WCAP + (unsigned)gb[tid];
        for (int i = 0; i < cw; ++i) {
            comp[lo + i] = lbins[tid * CAPB + i];
            dsti[lo + i] = wb + i;
        }
    }
    __syncthreads();

    for (int i = tid; i < T; i += 256)
        bins[dsti[i]] = comp[i];
}

// buildB with self-computed bucket base
__global__ __launch_bounds__(256) void buildB_kernel(
        const int* __restrict__ bcnt, const unsigned* __restrict__ bins,
        int* __restrict__ row_ptr, int* __restrict__ sorted_src,
        float* __restrict__ dinv)
{
    __shared__ unsigned ent[16384];
    __shared__ int scnt[XSL], soff[XSL];
    __shared__ int cnt[512], lofs[512], cur[512];
    __shared__ int sd[256];
    __shared__ int gbase_s;

    const int b   = blockIdx.x;
    const int tid = threadIdx.x;
    const int node0 = b * 512;

    int part = 0;
    for (int w = tid; w < b * XSL; w += 256) part += min(bcnt[w], WCAP);
    sd[tid] = part;
    __syncthreads();
    for (int off = 128; off > 0; off >>= 1) {
        if (tid < off) sd[tid] += sd[tid + off];
        __syncthreads();
    }
    if (tid == 0) {
        gbase_s = sd[0];
        if (b == 0) row_ptr[N_NODES] = N_EDGES;
    }
    __syncthreads();

    if (tid < XSL) scnt[tid] = min(bcnt[b * XSL + tid], WCAP);
    { int i = tid; cnt[i] = 0; cnt[i + 256] = 0; }
    __syncthreads();
    if (tid == 0) {
        int acc = 0;
        for (int sl = 0; sl < XSL; ++sl) {
            soff[sl] = acc;
            acc += scnt[sl];
            if (acc > 16384) { scnt[sl] -= (acc - 16384); acc = 16384; } // unreachable
        }
    }
    __syncthreads();

    for (int sl = 0; sl < XSL; ++sl) {
        int len = scnt[sl];
        const unsigned* seg = bins + (unsigned)(b * XSL + sl) * WCAP;
        int base = soff[sl];
        for (int i = tid; i < len; i += 256) {
            unsigned e = seg[i];
            ent[base + i] = e;
            atomicAdd((unsigned*)&cnt[e >> 17], 1u);
        }
    }
    __syncthreads();
    const int T = soff[XSL - 1] + scnt[XSL - 1];

    int a0 = cnt[2 * tid], a1 = cnt[2 * tid + 1];
    int s2 = a0 + a1;
    sd[tid] = s2;
    __syncthreads();
    for (int off = 1; off < 256; off <<= 1) {
        int x = 0;
        if (tid >= off) x = sd[tid - off];
        __syncthreads();
        if (tid >= off) sd[tid] += x;
        __syncthreads();
    }
    int excl = sd[tid] - s2;
    lofs[2 * tid]     = excl;
    lofs[2 * tid + 1] = excl + a0;
    cur[2 * tid]      = excl;
    cur[2 * tid + 1]  = excl + a0;
    __syncthreads();

    const int gbase = gbase_s;
    for (int j = tid; j < 512; j += 256) {
        int node = node0 + j;
        if (node < N_NODES) {
            row_ptr[node] = gbase + lofs[j];
            dinv[node] = 1.0f / (float)max(cnt[j], 1);
        }
    }
    for (int i = tid; i < T; i += 256) {
        unsigned e = ent[i];
        int dl = e >> 17;
        int p = atomicAdd((unsigned*)&cur[dl], 1u);
        sorted_src[gbase + p] = (int)(e & 0x1FFFFu);
    }
}

// ---- gather1: mean(xb[src]) -> agg1b (round-7 proven shape) ---------------
__global__ __launch_bounds__(256) void gather1_kernel(
        const int* __restrict__ row_ptr, const int* __restrict__ srcs,
        const unsigned short* __restrict__ featb,  // [N][64] bf16
        const float* __restrict__ dinv, unsigned short* __restrict__ aggb)
{
    int gid = blockIdx.x * 256 + threadIdx.x;
    int n = gid >> 3;
    int q = gid & 7;
    const uint4* f4 = (const uint4*)featb;
    float a0=0,a1=0,a2=0,a3=0,a4=0,a5=0,a6=0,a7=0;
    int beg = row_ptr[n];
    int end = row_ptr[n + 1];
    int e = beg;
    for (; e + 4 <= end; e += 4) {
        int s0 = srcs[e], s1 = srcs[e+1], s2 = srcs[e+2], s3 = srcs[e+3];
        uint4 v0 = f4[(size_t)s0 * 8 + q];
        uint4 v1 = f4[(size_t)s1 * 8 + q];
        uint4 v2 = f4[(size_t)s2 * 8 + q];
        uint4 v3 = f4[(size_t)s3 * 8 + q];
        ACC8(v0); ACC8(v1); ACC8(v2); ACC8(v3);
    }
    for (; e < end; ++e) {
        uint4 v = f4[(size_t)srcs[e] * 8 + q];
        ACC8(v);
    }
    float di = dinv[n];
    uint4 r;
    r.x = pk2(a0 * di, a1 * di);
    r.y = pk2(a2 * di, a3 * di);
    r.z = pk2(a4 * di, a5 * di);
    r.w = pk2(a6 * di, a7 * di);
    ((uint4*)aggb)[(size_t)n * 8 + q] = r;
}

// ---- mlp1: persistent-weight dense1 -> h1(LDS) -> {t2; s2} ----------------
// Weights are lane-invariant: loaded ONCE per block into 128 VGPRs
// (launch_bounds(256,2) -> 256-VGPR budget), then each block loops over
// ~6 node-tiles streaming only per-tile inputs, prefetched one tile ahead.
__global__ __launch_bounds__(256, 2) void mlp1_kernel(
        const unsigned short* __restrict__ xb,    // [N][64]
        const unsigned short* __restrict__ aggb,  // [N][64]
        const unsigned short* __restrict__ wt1s,  // [128][64]
        const unsigned short* __restrict__ wt1n,  // [128][64]
        const float* __restrict__ b1,             // [128]
        const unsigned short* __restrict__ wt2n,  // [64][128]
        const unsigned short* __restrict__ wt2s,  // [64][128]
        const float* __restrict__ b2,             // [64]
        unsigned short* __restrict__ t2b,         // [N][64]
        unsigned short* __restrict__ s2b)         // [N][64]
{
    __shared__ unsigned short sbuf[32 * 136];   // h1 (pitch 136 shorts)

    const int tid  = threadIdx.x;
    const int lane = tid & 63;
    const int wv   = tid >> 6;               // 0..3
    const int quad = lane >> 4;
    const int col  = lane & 15;
    const int nrow = (wv & 1) * 16 + col;    // local node 0..31
    const int mhalf = wv >> 1;               // 0..1

    // ---- hoist all weight fragments (loop-invariant, 32 x short8) ----
    short8 wBs0[4], wBs1[4], wBn0[4], wBn1[4];
#pragma unroll
    for (int mt = 0; mt < 4; ++mt) {
        size_t m = (size_t)((mhalf * 4 + mt) * 16 + col);
        wBs0[mt] = *(const short8*)(wt1s + m * 64 +      quad * 8);
        wBs1[mt] = *(const short8*)(wt1s + m * 64 + 32 + quad * 8);
        wBn0[mt] = *(const short8*)(wt1n + m * 64 +      quad * 8);
        wBn1[mt] = *(const short8*)(wt1n + m * 64 + 32 + quad * 8);
    }
    short8 wCt[2][4], wCs[2][4];
#pragma unroll
    for (int mt = 0; mt < 2; ++mt) {
        size_t m = (size_t)((mhalf * 2 + mt) * 16 + col);
#pragma unroll
        for (int kc = 0; kc < 4; ++kc) {
            wCt[mt][kc] = *(const short8*)(wt2n + m * 128 + kc * 32 + quad * 8);
            wCs[mt][kc] = *(const short8*)(wt2s + m * 128 + kc * 32 + quad * 8);
        }
    }
    float4 bv1[4];
#pragma unroll
    for (int mt = 0; mt < 4; ++mt)
        bv1[mt] = *(const float4*)(b1 + (mhalf * 4 + mt) * 16 + quad * 4);
    float4 bv2[2];
#pragma unroll
    for (int mt = 0; mt < 2; ++mt)
        bv2[mt] = *(const float4*)(b2 + (mhalf * 2 + mt) * 16 + quad * 4);

    // ---- persistent tile loop with 1-tile input prefetch ----
    int tile = blockIdx.x;
    short8 bs0, bs1, bn0, bn1;
    {
        const int nl = tile * 32 + nrow;
        bs0 = *(const short8*)(xb   + (size_t)nl * 64 +      quad * 8);
        bs1 = *(const short8*)(xb   + (size_t)nl * 64 + 32 + quad * 8);
        bn0 = *(const short8*)(aggb + (size_t)nl * 64 +      quad * 8);
        bn1 = *(const short8*)(aggb + (size_t)nl * 64 + 32 + quad * 8);
    }

    while (tile < NTILES) {
        const int nl = tile * 32 + nrow;
        const int next = tile + MLP_GRID;

        // phase B: dense1 into accB (consumes bs*/bn*)
        floatx4 accB[4];
#pragma unroll
        for (int mt = 0; mt < 4; ++mt) {
            floatx4 acc = {0.f, 0.f, 0.f, 0.f};
            acc = __builtin_amdgcn_mfma_f32_16x16x32_bf16(wBs0[mt], bs0, acc, 0, 0, 0);
            acc = __builtin_amdgcn_mfma_f32_16x16x32_bf16(wBs1[mt], bs1, acc, 0, 0, 0);
            acc = __builtin_amdgcn_mfma_f32_16x16x32_bf16(wBn0[mt], bn0, acc, 0, 0, 0);
            acc = __builtin_amdgcn_mfma_f32_16x16x32_bf16(wBn1[mt], bn1, acc, 0, 0, 0);
            accB[mt] = acc;
        }

        // prefetch next tile's inputs (overlaps barrier + phase C)
        if (next < NTILES) {
            const int nn = next * 32 + nrow;
            bs0 = *(const short8*)(xb   + (size_t)nn * 64 +      quad * 8);
            bs1 = *(const short8*)(xb   + (size_t)nn * 64 + 32 + quad * 8);
            bn0 = *(const short8*)(aggb + (size_t)nn * 64 +      quad * 8);
            bn1 = *(const short8*)(aggb + (size_t)nn * 64 + 32 + quad * 8);
        }

        __syncthreads();   // prev tile's phase-C sbuf reads complete
#pragma unroll
        for (int mt = 0; mt < 4; ++mt) {
            int och = (mhalf * 4 + mt) * 16 + quad * 4;
            ushort4 r;
            r.x = f2bf(fmaxf(accB[mt][0] + bv1[mt].x, 0.f));
            r.y = f2bf(fmaxf(accB[mt][1] + bv1[mt].y, 0.f));
            r.z = f2bf(fmaxf(accB[mt][2] + bv1[mt].z, 0.f));
            r.w = f2bf(fmaxf(accB[mt][3] + bv1[mt].w, 0.f));
            *(ushort4*)(sbuf + nrow * 136 + och) = r;
        }
        __syncthreads();

        // phase C: t2 = Wn2.h1 ; s2 = Ws2.h1 + b2
        short8 bfr[4];
#pragma unroll
        for (int kc = 0; kc < 4; ++kc)
            bfr[kc] = *(const short8*)(sbuf + nrow * 136 + kc * 32 + quad * 8);
#pragma unroll
        for (int mt = 0; mt < 2; ++mt) {
            floatx4 at = {0.f, 0.f, 0.f, 0.f};
            floatx4 as = {0.f, 0.f, 0.f, 0.f};
#pragma unroll
            for (int kc = 0; kc < 4; ++kc) {
                at = __builtin_amdgcn_mfma_f32_16x16x32_bf16(wCt[mt][kc], bfr[kc], at, 0, 0, 0);
                as = __builtin_amdgcn_mfma_f32_16x16x32_bf16(wCs[mt][kc], bfr[kc], as, 0, 0, 0);
            }
            int och = (mhalf * 2 + mt) * 16 + quad * 4;
            ushort4 rt;
            rt.x = f2bf(at[0]); rt.y = f2bf(at[1]);
            rt.z = f2bf(at[2]); rt.w = f2bf(at[3]);
            *(ushort4*)(t2b + (size_t)nl * 64 + och) = rt;
            ushort4 rs;
            rs.x = f2bf(as[0] + bv2[mt].x); rs.y = f2bf(as[1] + bv2[mt].y);
            rs.z = f2bf(as[2] + bv2[mt].z); rs.w = f2bf(as[3] + bv2[mt].w);
            *(ushort4*)(s2b + (size_t)nl * 64 + och) = rs;
        }

        tile = next;
    }
}

// ---- fused2: gather(t2) + relu(s2+agg) -> classifier ----------------------
__global__ __launch_bounds__(256, 8) void fused2_kernel(
        const int* __restrict__ row_ptr, const int* __restrict__ srcs,
        const unsigned short* __restrict__ t2b,   // [N][64]
        const unsigned short* __restrict__ s2b,   // [N][64]
        const float* __restrict__ dinv,
        const float* __restrict__ wc,             // [64][20]
        const float* __restrict__ bc,             // [20]
        float* __restrict__ out)                  // [N][20]
{
    __shared__ float hs[32][68];

    const int tid = threadIdx.x;
    const int node0 = blockIdx.x * 32;

    // ---- phase A: gather mean(t2[src]) + s2 + relu -> hs (fp32) ----
    {
        const int q  = tid & 7;
        const int np = tid >> 3;   // 0..31
        const int n = node0 + np;
        const uint4* f4 = (const uint4*)t2b;
        float a0=0,a1=0,a2=0,a3=0,a4=0,a5=0,a6=0,a7=0;
        int beg = row_ptr[n];
        int end = row_ptr[n + 1];
        int e = beg;
        for (; e + 4 <= end; e += 4) {
            int s0 = srcs[e], s1 = srcs[e+1], s2 = srcs[e+2], s3 = srcs[e+3];
            uint4 v0 = f4[(size_t)s0 * 8 + q];
            uint4 v1 = f4[(size_t)s1 * 8 + q];
            uint4 v2 = f4[(size_t)s2 * 8 + q];
            uint4 v3 = f4[(size_t)s3 * 8 + q];
            ACC8(v0); ACC8(v1); ACC8(v2); ACC8(v3);
        }
        for (; e < end; ++e) {
            uint4 v = f4[(size_t)srcs[e] * 8 + q];
            ACC8(v);
        }
        float di = dinv[n];
        uint4 sv = *(const uint4*)(s2b + (size_t)n * 64 + q * 8);
        float* d = hs[np] + q * 8;
        d[0] = fmaxf(a0 * di + bflo(sv.x), 0.f);
        d[1] = fmaxf(a1 * di + bfhi(sv.x), 0.f);
        d[2] = fmaxf(a2 * di + bflo(sv.y), 0.f);
        d[3] = fmaxf(a3 * di + bfhi(sv.y), 0.f);
        d[4] = fmaxf(a4 * di + bflo(sv.z), 0.f);
        d[5] = fmaxf(a5 * di + bfhi(sv.z), 0.f);
        d[6] = fmaxf(a6 * di + bflo(sv.w), 0.f);
        d[7] = fmaxf(a7 * di + bfhi(sv.w), 0.f);
    }
    __syncthreads();

    // ---- phase B: classifier (wc/bc direct from global, L1-hot) ----
    for (int o = tid; o < 32 * N_CLS; o += 256) {
        int n = o / N_CLS, cls = o % N_CLS;
        float s = bc[cls];
#pragma unroll
        for (int k = 0; k < 64; ++k) s += hs[n][k] * wc[k * N_CLS + cls];
        out[(size_t)(node0 + n) * N_CLS + cls] = s;
    }
}

// ---------------------------------------------------------------------------

extern "C" void kernel_launch(void* const* d_in, const int* in_sizes, int n_in,
                              void* d_out, int out_size, void* d_ws, size_t ws_size,
                              hipStream_t stream)
{
    const float* x        = (const float*)d_in[0];
    const int*   ei       = (const int*)  d_in[1];
    const float* w_self1  = (const float*)d_in[2];
    const float* w_neigh1 = (const float*)d_in[3];
    const float* b1       = (const float*)d_in[4];
    const float* w_self2  = (const float*)d_in[5];
    const float* w_neigh2 = (const float*)d_in[6];
    const float* b2       = (const float*)d_in[7];
    const float* wc       = (const float*)d_in[8];
    const float* bc       = (const float*)d_in[9];
    float* out = (float*)d_out;

    const size_t N = N_NODES;
    int*      bcnt    = (int*)d_ws;                       // BUCKETS*XSL
    int*      row_ptr = bcnt + BUCKETS * XSL + 8;         // N+8
    unsigned* bins    = (unsigned*)(row_ptr + N + 8);     // BUCKETS*XSL*WCAP
    int*      s_src   = (int*)(bins + BUCKETS * XSL * WCAP);  // E
    float*    dinv    = (float*)(s_src + N_EDGES);        // N
    unsigned short* xb    = (unsigned short*)(dinv + N);  // [N][64]
    unsigned short* agg1b = xb + 64 * N;                  // [N][64]
    unsigned short* t2b   = agg1b + 64 * N;               // [N][64]
    unsigned short* s2b   = t2b + 64 * N;                 // [N][64]
    unsigned short* wt1s  = s2b + 64 * N;                 // 128x64
    unsigned short* wt1n  = wt1s + 8192;
    unsigned short* wt2s  = wt1n + 8192;                  // 64x128
    unsigned short* wt2n  = wt2s + 8192;

    const int PB  = CVT_BLOCKS + 1 + 64;           // prologue blocks
    const int EB2 = (N_EDGES + EPB - 1) / EPB;     // 391
    const int GB  = (N_NODES * 8) / 256;           // 3125 (exact)
    const int MB32 = (N_NODES + 31) / 32;          // 3125 (exact)

    prologue_kernel<<<PB, 256, 0, stream>>>(x, w_self1, w_neigh1, w_self2,
                                            w_neigh2, xb, wt1s, wt1n, wt2s,
                                            wt2n, bcnt);
    binA_kernel<<<EB2, 256, 0, stream>>>(ei, bcnt, bins);
    buildB_kernel<<<BUCKETS, 256, 0, stream>>>(bcnt, bins, row_ptr, s_src, dinv);
    gather1_kernel<<<GB, 256, 0, stream>>>(row_ptr, s_src, xb, dinv, agg1b);
    mlp1_kernel<<<MLP_GRID, 256, 0, stream>>>(xb, agg1b, wt1s, wt1n, b1,
                                              wt2n, wt2s, b2, t2b, s2b);
    fused2_kernel<<<MB32, 256, 0, stream>>>(row_ptr, s_src, t2b, s2b, dinv,
                                            wc, bc, out);
}

// Round 14
// 262.881 us; speedup vs baseline: 1.1621x; 1.0031x over previous
//
#include <hip/hip_runtime.h>

#define N_NODES 100000
#define N_EDGES 1600000
#define IN_C    64
#define HID_C   128
#define OUT_C   64
#define N_CLS   20

#define BUCKETS 196          // ceil(N_NODES / 512), 512 nodes per bucket
#define XSL     8            // one slice per XCD (blockIdx & 7)
#define WCAP    2560         // per (bucket,xcd) window; mean 1020, huge margin
#define EPB     4096         // edges per binA block
#define CAPB    44           // per-block per-bucket LDS cap; mean 20.9, +5sig

#define EB2       391        // binning blocks
#define CVT_BLOCKS 3125      // N_NODES*64/8/256
#define NTILES    3125       // 32-node tiles (exact)
#define MLP_GRID  512        // persistent mlp blocks (2 per CU)

typedef __attribute__((ext_vector_type(8))) short short8;   // 8 bf16 = 4 VGPR
typedef __attribute__((ext_vector_type(4))) float floatx4;  // MFMA acc

__device__ __forceinline__ unsigned short f2bf(float f) {  // RNE
    union { float f; unsigned u; } v; v.f = f;
    unsigned r = v.u + 0x7FFFu + ((v.u >> 16) & 1u);
    return (unsigned short)(r >> 16);
}
__device__ __forceinline__ unsigned pk2(float lo, float hi) {
    return (unsigned)f2bf(lo) | ((unsigned)f2bf(hi) << 16);
}
__device__ __forceinline__ float bflo(unsigned w) { return __uint_as_float(w << 16); }
__device__ __forceinline__ float bfhi(unsigned w) { return __uint_as_float(w & 0xFFFF0000u); }

#define ACC8(v) do { \
    a0 += bflo((v).x); a1 += bfhi((v).x); a2 += bflo((v).y); a3 += bfhi((v).y); \
    a4 += bflo((v).z); a5 += bfhi((v).z); a6 += bflo((v).w); a7 += bfhi((v).w); } while (0)

// ---- binA merged with cvt_x + prep_wt (independent work, one launch) ------
// Blocks [0,EB2): edge binning (LDS-local, 1 global atomic per bucket).
// Blocks [EB2, EB2+CVT_BLOCKS): x fp32 -> bf16. Last 64 blocks: weight prep.
// bcnt must be zeroed BEFORE this kernel (hipMemsetAsync) - binning atomics.
__global__ __launch_bounds__(256) void binA_kernel(
        const int* __restrict__ ei, int* __restrict__ bcnt,
        unsigned* __restrict__ bins,
        const float* __restrict__ x, unsigned short* __restrict__ xb,
        const float* __restrict__ ws1, const float* __restrict__ wn1,
        const float* __restrict__ ws2, const float* __restrict__ wn2,
        unsigned short* __restrict__ wt1s, unsigned short* __restrict__ wt1n,
        unsigned short* __restrict__ wt2s, unsigned short* __restrict__ wt2n)
{
    __shared__ unsigned lbins[BUCKETS * CAPB];
    __shared__ unsigned comp[EPB];
    __shared__ unsigned dsti[EPB];
    __shared__ int lcnt[BUCKETS], lofs[BUCKETS], gb[BUCKETS];
    __shared__ int sd[256];

    const int bid = blockIdx.x;
    const int tid = threadIdx.x;

    if (bid >= EB2) {                       // ---- cvt / weight-prep blocks
        if (bid < EB2 + CVT_BLOCKS) {
            int i = (bid - EB2) * 256 + tid;    // < 800000 exactly
            float4 a = ((const float4*)x)[(size_t)i * 2];
            float4 b = ((const float4*)x)[(size_t)i * 2 + 1];
            uint4 r;
            r.x = pk2(a.x, a.y); r.y = pk2(a.z, a.w);
            r.z = pk2(b.x, b.y); r.w = pk2(b.z, b.w);
            ((uint4*)xb)[i] = r;
        } else {
            int i = (bid - EB2 - CVT_BLOCKS) * 256 + tid;
            if (i < 8192) {                 // layer 1: [128][64]
                int o = i >> 6, c = i & 63;
                wt1s[i] = f2bf(ws1[c * 128 + o]);
                wt1n[i] = f2bf(wn1[c * 128 + o]);
            } else if (i < 16384) {         // layer 2: [64][128]
                int j = i - 8192;
                int o = j >> 7, c = j & 127;
                wt2s[j] = f2bf(ws2[c * 64 + o]);
                wt2n[j] = f2bf(wn2[c * 64 + o]);
            }
        }
        return;
    }

    // ---- edge binning (round-5 proven design) ----
    const int xcd = bid & (XSL - 1);
    const int e0  = bid * EPB;

    for (int w = tid; w < BUCKETS; w += 256) lcnt[w] = 0;
    __syncthreads();

    for (int it = 0; it < EPB / 256; ++it) {
        int e = e0 + it * 256 + tid;
        if (e >= N_EDGES) break;
        int src = ei[e];
        int dst = ei[N_EDGES + e];
        int b = dst >> 9;
        unsigned pk = ((unsigned)(dst & 511) << 17) | (unsigned)src;
        int pos = atomicAdd(&lcnt[b], 1);
        if (pos < CAPB) {
            lbins[b * CAPB + pos] = pk;
        } else {  // rare fallback: direct global append (always correct)
            int gp = atomicAdd(&bcnt[b * XSL + xcd], 1);
            if (gp < WCAP)
                bins[(unsigned)(b * XSL + xcd) * WCAP + gp] = pk;
        }
    }
    __syncthreads();

    int c = (tid < BUCKETS) ? min(lcnt[tid], CAPB) : 0;
    sd[tid] = c;
    __syncthreads();
    for (int off = 1; off < 256; off <<= 1) {
        int v = 0;
        if (tid >= off) v = sd[tid - off];
        __syncthreads();
        if (tid >= off) sd[tid] += v;
        __syncthreads();
    }
    if (tid < BUCKETS) lofs[tid] = sd[tid] - c;
    __syncthreads();
    const int T = sd[255];

    if (tid < BUCKETS) {
        int cw = min(lcnt[tid], CAPB);
        gb[tid] = (cw > 0) ? atomicAdd(&bcnt[tid * XSL + xcd], cw) : 0;
    }
    __syncthreads();

    if (tid < BUCKETS) {
        int cw = min(lcnt[tid], CAPB);
        int lo = lofs[tid];
        unsigned wb = (unsigned)(tid * XSL + xcd) * WCAP + (unsigned)gb[tid];
        for (int i = 0; i < cw; ++i) {
            comp[lo + i] = lbins[tid * CAPB + i];
            dsti[lo + i] = wb + i;
        }
    }
    __syncthreads();

    for (int i = tid; i < T; i += 256)
        bins[dsti[i]] = comp[i];
}

// buildB with self-computed bucket base
__global__ __launch_bounds__(256) void buildB_kernel(
        const int* __restrict__ bcnt, const unsigned* __restrict__ bins,
        int* __restrict__ row_ptr, int* __restrict__ sorted_src,
        float* __restrict__ dinv)
{
    __shared__ unsigned ent[16384];
    __shared__ int scnt[XSL], soff[XSL];
    __shared__ int cnt[512], lofs[512], cur[512];
    __shared__ int sd[256];
    __shared__ int gbase_s;

    const int b   = blockIdx.x;
    const int tid = threadIdx.x;
    const int node0 = b * 512;

    int part = 0;
    for (int w = tid; w < b * XSL; w += 256) part += min(bcnt[w], WCAP);
    sd[tid] = part;
    __syncthreads();
    for (int off = 128; off > 0; off >>= 1) {
        if (tid < off) sd[tid] += sd[tid + off];
        __syncthreads();
    }
    if (tid == 0) {
        gbase_s = sd[0];
        if (b == 0) row_ptr[N_NODES] = N_EDGES;
    }
    __syncthreads();

    if (tid < XSL) scnt[tid] = min(bcnt[b * XSL + tid], WCAP);
    { int i = tid; cnt[i] = 0; cnt[i + 256] = 0; }
    __syncthreads();
    if (tid == 0) {
        int acc = 0;
        for (int sl = 0; sl < XSL; ++sl) {
            soff[sl] = acc;
            acc += scnt[sl];
            if (acc > 16384) { scnt[sl] -= (acc - 16384); acc = 16384; } // unreachable
        }
    }
    __syncthreads();

    for (int sl = 0; sl < XSL; ++sl) {
        int len = scnt[sl];
        const unsigned* seg = bins + (unsigned)(b * XSL + sl) * WCAP;
        int base = soff[sl];
        for (int i = tid; i < len; i += 256) {
            unsigned e = seg[i];
            ent[base + i] = e;
            atomicAdd((unsigned*)&cnt[e >> 17], 1u);
        }
    }
    __syncthreads();
    const int T = soff[XSL - 1] + scnt[XSL - 1];

    int a0 = cnt[2 * tid], a1 = cnt[2 * tid + 1];
    int s2 = a0 + a1;
    sd[tid] = s2;
    __syncthreads();
    for (int off = 1; off < 256; off <<= 1) {
        int v = 0;
        if (tid >= off) v = sd[tid - off];
        __syncthreads();
        if (tid >= off) sd[tid] += v;
        __syncthreads();
    }
    int excl = sd[tid] - s2;
    lofs[2 * tid]     = excl;
    lofs[2 * tid + 1] = excl + a0;
    cur[2 * tid]      = excl;
    cur[2 * tid + 1]  = excl + a0;
    __syncthreads();

    const int gbase = gbase_s;
    for (int j = tid; j < 512; j += 256) {
        int node = node0 + j;
        if (node < N_NODES) {
            row_ptr[node] = gbase + lofs[j];
            dinv[node] = 1.0f / (float)max(cnt[j], 1);
        }
    }
    for (int i = tid; i < T; i += 256) {
        unsigned e = ent[i];
        int dl = e >> 17;
        int p = atomicAdd((unsigned*)&cur[dl], 1u);
        sorted_src[gbase + p] = (int)(e & 0x1FFFFu);
    }
}

// ---- gather1: mean(xb[src]) -> agg1b (round-7 proven shape) ---------------
__global__ __launch_bounds__(256) void gather1_kernel(
        const int* __restrict__ row_ptr, const int* __restrict__ srcs,
        const unsigned short* __restrict__ featb,  // [N][64] bf16
        const float* __restrict__ dinv, unsigned short* __restrict__ aggb)
{
    int gid = blockIdx.x * 256 + threadIdx.x;
    int n = gid >> 3;
    int q = gid & 7;
    const uint4* f4 = (const uint4*)featb;
    float a0=0,a1=0,a2=0,a3=0,a4=0,a5=0,a6=0,a7=0;
    int beg = row_ptr[n];
    int end = row_ptr[n + 1];
    int e = beg;
    for (; e + 4 <= end; e += 4) {
        int s0 = srcs[e], s1 = srcs[e+1], s2 = srcs[e+2], s3 = srcs[e+3];
        uint4 v0 = f4[(size_t)s0 * 8 + q];
        uint4 v1 = f4[(size_t)s1 * 8 + q];
        uint4 v2 = f4[(size_t)s2 * 8 + q];
        uint4 v3 = f4[(size_t)s3 * 8 + q];
        ACC8(v0); ACC8(v1); ACC8(v2); ACC8(v3);
    }
    for (; e < end; ++e) {
        uint4 v = f4[(size_t)srcs[e] * 8 + q];
        ACC8(v);
    }
    float di = dinv[n];
    uint4 r;
    r.x = pk2(a0 * di, a1 * di);
    r.y = pk2(a2 * di, a3 * di);
    r.z = pk2(a4 * di, a5 * di);
    r.w = pk2(a6 * di, a7 * di);
    ((uint4*)aggb)[(size_t)n * 8 + q] = r;
}

// ---- mlp1: persistent-weight dense1 -> h1(LDS) -> {t2; s2} ----------------
__global__ __launch_bounds__(256, 2) void mlp1_kernel(
        const unsigned short* __restrict__ xb,    // [N][64]
        const unsigned short* __restrict__ aggb,  // [N][64]
        const unsigned short* __restrict__ wt1s,  // [128][64]
        const unsigned short* __restrict__ wt1n,  // [128][64]
        const float* __restrict__ b1,             // [128]
        const unsigned short* __restrict__ wt2n,  // [64][128]
        const unsigned short* __restrict__ wt2s,  // [64][128]
        const float* __restrict__ b2,             // [64]
        unsigned short* __restrict__ t2b,         // [N][64]
        unsigned short* __restrict__ s2b)         // [N][64]
{
    __shared__ unsigned short sbuf[32 * 136];   // h1 (pitch 136 shorts)

    const int tid  = threadIdx.x;
    const int lane = tid & 63;
    const int wv   = tid >> 6;               // 0..3
    const int quad = lane >> 4;
    const int col  = lane & 15;
    const int nrow = (wv & 1) * 16 + col;    // local node 0..31
    const int mhalf = wv >> 1;               // 0..1

    // ---- hoist all weight fragments (loop-invariant, 32 x short8) ----
    short8 wBs0[4], wBs1[4], wBn0[4], wBn1[4];
#pragma unroll
    for (int mt = 0; mt < 4; ++mt) {
        size_t m = (size_t)((mhalf * 4 + mt) * 16 + col);
        wBs0[mt] = *(const short8*)(wt1s + m * 64 +      quad * 8);
        wBs1[mt] = *(const short8*)(wt1s + m * 64 + 32 + quad * 8);
        wBn0[mt] = *(const short8*)(wt1n + m * 64 +      quad * 8);
        wBn1[mt] = *(const short8*)(wt1n + m * 64 + 32 + quad * 8);
    }
    short8 wCt[2][4], wCs[2][4];
#pragma unroll
    for (int mt = 0; mt < 2; ++mt) {
        size_t m = (size_t)((mhalf * 2 + mt) * 16 + col);
#pragma unroll
        for (int kc = 0; kc < 4; ++kc) {
            wCt[mt][kc] = *(const short8*)(wt2n + m * 128 + kc * 32 + quad * 8);
            wCs[mt][kc] = *(const short8*)(wt2s + m * 128 + kc * 32 + quad * 8);
        }
    }
    float4 bv1[4];
#pragma unroll
    for (int mt = 0; mt < 4; ++mt)
        bv1[mt] = *(const float4*)(b1 + (mhalf * 4 + mt) * 16 + quad * 4);
    float4 bv2[2];
#pragma unroll
    for (int mt = 0; mt < 2; ++mt)
        bv2[mt] = *(const float4*)(b2 + (mhalf * 2 + mt) * 16 + quad * 4);

    // ---- persistent tile loop with 1-tile input prefetch ----
    int tile = blockIdx.x;
    short8 bs0, bs1, bn0, bn1;
    {
        const int nl = tile * 32 + nrow;
        bs0 = *(const short8*)(xb   + (size_t)nl * 64 +      quad * 8);
        bs1 = *(const short8*)(xb   + (size_t)nl * 64 + 32 + quad * 8);
        bn0 = *(const short8*)(aggb + (size_t)nl * 64 +      quad * 8);
        bn1 = *(const short8*)(aggb + (size_t)nl * 64 + 32 + quad * 8);
    }

    while (tile < NTILES) {
        const int nl = tile * 32 + nrow;
        const int next = tile + MLP_GRID;

        floatx4 accB[4];
#pragma unroll
        for (int mt = 0; mt < 4; ++mt) {
            floatx4 acc = {0.f, 0.f, 0.f, 0.f};
            acc = __builtin_amdgcn_mfma_f32_16x16x32_bf16(wBs0[mt], bs0, acc, 0, 0, 0);
            acc = __builtin_amdgcn_mfma_f32_16x16x32_bf16(wBs1[mt], bs1, acc, 0, 0, 0);
            acc = __builtin_amdgcn_mfma_f32_16x16x32_bf16(wBn0[mt], bn0, acc, 0, 0, 0);
            acc = __builtin_amdgcn_mfma_f32_16x16x32_bf16(wBn1[mt], bn1, acc, 0, 0, 0);
            accB[mt] = acc;
        }

        if (next < NTILES) {
            const int nn = next * 32 + nrow;
            bs0 = *(const short8*)(xb   + (size_t)nn * 64 +      quad * 8);
            bs1 = *(const short8*)(xb   + (size_t)nn * 64 + 32 + quad * 8);
            bn0 = *(const short8*)(aggb + (size_t)nn * 64 +      quad * 8);
            bn1 = *(const short8*)(aggb + (size_t)nn * 64 + 32 + quad * 8);
        }

        __syncthreads();   // prev tile's phase-C sbuf reads complete
#pragma unroll
        for (int mt = 0; mt < 4; ++mt) {
            int och = (mhalf * 4 + mt) * 16 + quad * 4;
            ushort4 r;
            r.x = f2bf(fmaxf(accB[mt][0] + bv1[mt].x, 0.f));
            r.y = f2bf(fmaxf(accB[mt][1] + bv1[mt].y, 0.f));
            r.z = f2bf(fmaxf(accB[mt][2] + bv1[mt].z, 0.f));
            r.w = f2bf(fmaxf(accB[mt][3] + bv1[mt].w, 0.f));
            *(ushort4*)(sbuf + nrow * 136 + och) = r;
        }
        __syncthreads();

        short8 bfr[4];
#pragma unroll
        for (int kc = 0; kc < 4; ++kc)
            bfr[kc] = *(const short8*)(sbuf + nrow * 136 + kc * 32 + quad * 8);
#pragma unroll
        for (int mt = 0; mt < 2; ++mt) {
            floatx4 at = {0.f, 0.f, 0.f, 0.f};
            floatx4 as = {0.f, 0.f, 0.f, 0.f};
#pragma unroll
            for (int kc = 0; kc < 4; ++kc) {
                at = __builtin_amdgcn_mfma_f32_16x16x32_bf16(wCt[mt][kc], bfr[kc], at, 0, 0, 0);
                as = __builtin_amdgcn_mfma_f32_16x16x32_bf16(wCs[mt][kc], bfr[kc], as, 0, 0, 0);
            }
            int och = (mhalf * 2 + mt) * 16 + quad * 4;
            ushort4 rt;
            rt.x = f2bf(at[0]); rt.y = f2bf(at[1]);
            rt.z = f2bf(at[2]); rt.w = f2bf(at[3]);
            *(ushort4*)(t2b + (size_t)nl * 64 + och) = rt;
            ushort4 rs;
            rs.x = f2bf(as[0] + bv2[mt].x); rs.y = f2bf(as[1] + bv2[mt].y);
            rs.z = f2bf(as[2] + bv2[mt].z); rs.w = f2bf(as[3] + bv2[mt].w);
            *(ushort4*)(s2b + (size_t)nl * 64 + och) = rs;
        }

        tile = next;
    }
}

// ---- fused2: gather(t2) + relu(s2+agg) -> classifier ----------------------
__global__ __launch_bounds__(256, 8) void fused2_kernel(
        const int* __restrict__ row_ptr, const int* __restrict__ srcs,
        const unsigned short* __restrict__ t2b,   // [N][64]
        const unsigned short* __restrict__ s2b,   // [N][64]
        const float* __restrict__ dinv,
        const float* __restrict__ wc,             // [64][20]
        const float* __restrict__ bc,             // [20]
        float* __restrict__ out)                  // [N][20]
{
    __shared__ float hs[32][68];

    const int tid = threadIdx.x;
    const int node0 = blockIdx.x * 32;

    // ---- phase A: gather mean(t2[src]) + s2 + relu -> hs (fp32) ----
    {
        const int q  = tid & 7;
        const int np = tid >> 3;   // 0..31
        const int n = node0 + np;
        const uint4* f4 = (const uint4*)t2b;
        // s2 + dinv prefetch: independent of the edge loop, issue first
        uint4 sv = *(const uint4*)(s2b + (size_t)n * 64 + q * 8);
        float di = dinv[n];
        float a0=0,a1=0,a2=0,a3=0,a4=0,a5=0,a6=0,a7=0;
        int beg = row_ptr[n];
        int end = row_ptr[n + 1];
        int e = beg;
        for (; e + 4 <= end; e += 4) {
            int s0 = srcs[e], s1 = srcs[e+1], s2 = srcs[e+2], s3 = srcs[e+3];
            uint4 v0 = f4[(size_t)s0 * 8 + q];
            uint4 v1 = f4[(size_t)s1 * 8 + q];
            uint4 v2 = f4[(size_t)s2 * 8 + q];
            uint4 v3 = f4[(size_t)s3 * 8 + q];
            ACC8(v0); ACC8(v1); ACC8(v2); ACC8(v3);
        }
        for (; e < end; ++e) {
            uint4 v = f4[(size_t)srcs[e] * 8 + q];
            ACC8(v);
        }
        float* d = hs[np] + q * 8;
        d[0] = fmaxf(a0 * di + bflo(sv.x), 0.f);
        d[1] = fmaxf(a1 * di + bfhi(sv.x), 0.f);
        d[2] = fmaxf(a2 * di + bflo(sv.y), 0.f);
        d[3] = fmaxf(a3 * di + bfhi(sv.y), 0.f);
        d[4] = fmaxf(a4 * di + bflo(sv.z), 0.f);
        d[5] = fmaxf(a5 * di + bfhi(sv.z), 0.f);
        d[6] = fmaxf(a6 * di + bflo(sv.w), 0.f);
        d[7] = fmaxf(a7 * di + bfhi(sv.w), 0.f);
    }
    __syncthreads();

    // ---- phase B: classifier (wc/bc direct from global, L1-hot) ----
    for (int o = tid; o < 32 * N_CLS; o += 256) {
        int n = o / N_CLS, cls = o % N_CLS;
        float s = bc[cls];
#pragma unroll
        for (int k = 0; k < 64; ++k) s += hs[n][k] * wc[k * N_CLS + cls];
        out[(size_t)(node0 + n) * N_CLS + cls] = s;
    }
}

// ---------------------------------------------------------------------------

extern "C" void kernel_launch(void* const* d_in, const int* in_sizes, int n_in,
                              void* d_out, int out_size, void* d_ws, size_t ws_size,
                              hipStream_t stream)
{
    const float* x        = (const float*)d_in[0];
    const int*   ei       = (const int*)  d_in[1];
    const float* w_self1  = (const float*)d_in[2];
    const float* w_neigh1 = (const float*)d_in[3];
    const float* b1       = (const float*)d_in[4];
    const float* w_self2  = (const float*)d_in[5];
    const float* w_neigh2 = (const float*)d_in[6];
    const float* b2       = (const float*)d_in[7];
    const float* wc       = (const float*)d_in[8];
    const float* bc       = (const float*)d_in[9];
    float* out = (float*)d_out;

    const size_t N = N_NODES;
    int*      bcnt    = (int*)d_ws;                       // BUCKETS*XSL
    int*      row_ptr = bcnt + BUCKETS * XSL + 8;         // N+8
    unsigned* bins    = (unsigned*)(row_ptr + N + 8);     // BUCKETS*XSL*WCAP
    int*      s_src   = (int*)(bins + BUCKETS * XSL * WCAP);  // E
    float*    dinv    = (float*)(s_src + N_EDGES);        // N
    unsigned short* xb    = (unsigned short*)(dinv + N);  // [N][64]
    unsigned short* agg1b = xb + 64 * N;                  // [N][64]
    unsigned short* t2b   = agg1b + 64 * N;               // [N][64]
    unsigned short* s2b   = t2b + 64 * N;                 // [N][64]
    unsigned short* wt1s  = s2b + 64 * N;                 // 128x64
    unsigned short* wt1n  = wt1s + 8192;
    unsigned short* wt2s  = wt1n + 8192;                  // 64x128
    unsigned short* wt2n  = wt2s + 8192;

    const int BA  = EB2 + CVT_BLOCKS + 64;         // merged binA grid
    const int GB  = (N_NODES * 8) / 256;           // 3125 (exact)
    const int MB32 = (N_NODES + 31) / 32;          // 3125 (exact)

    hipMemsetAsync(bcnt, 0, BUCKETS * XSL * sizeof(int), stream);
    binA_kernel<<<BA, 256, 0, stream>>>(ei, bcnt, bins, x, xb,
                                        w_self1, w_neigh1, w_self2, w_neigh2,
                                        wt1s, wt1n, wt2s, wt2n);
    buildB_kernel<<<BUCKETS, 256, 0, stream>>>(bcnt, bins, row_ptr, s_src, dinv);
    gather1_kernel<<<GB, 256, 0, stream>>>(row_ptr, s_src, xb, dinv, agg1b);
    mlp1_kernel<<<MLP_GRID, 256, 0, stream>>>(xb, agg1b, wt1s, wt1n, b1,
                                              wt2n, wt2s, b2, t2b, s2b);
    fused2_kernel<<<MB32, 256, 0, stream>>>(row_ptr, s_src, t2b, s2b, dinv,
                                            wc, bc, out);
}